// Round 1
// baseline (786.635 us; speedup 1.0000x reference)
//
#include <hip/hip_runtime.h>
#include <hip/hip_bf16.h>
#include <math.h>

#define N_NODES   100000
#define N_EDGES   3200000
#define IN_DIM    128
#define HID       64
#define OUT_DIM   10
#define N_GRAPHS  64

// Direct CSR build: row-histogram (global atomics, no return) -> scan ->
// scatter with returning global atomics. Cursor array = 400 KB (L2-resident);
// avg 32 edges/row -> 32-way contention spread over the whole dispatch.
#define EDGES_PER_THREAD 4
#define HIST_GRID  (N_EDGES / (256 * EDGES_PER_THREAD))           // 3125 (exact)
#define NSCAN_NODES ((N_NODES + 1023) / 1024)                     // 98

typedef unsigned long long ull;
typedef unsigned short ushort;
typedef __attribute__((ext_vector_type(8))) short short8;   // 8 bf16 (4 VGPRs)
typedef __attribute__((ext_vector_type(4))) float f32x4;    // MFMA C/D

__device__ __forceinline__ ushort rne_bf16(float x) {
    unsigned u = __float_as_uint(x);
    return (ushort)((u + 0x7fffu + ((u >> 16) & 1u)) >> 16);
}
__device__ __forceinline__ float bf2f(ushort u) {
    return __uint_as_float((unsigned)u << 16);
}

// ---------------------------------------------------------------- hist
// Per-row histogram with fire-and-forget global atomics.
__global__ __launch_bounds__(256) void hist_direct(const int* __restrict__ rows,
                                                   int* __restrict__ cnt) {
    int base = (blockIdx.x * 256 + threadIdx.x) * EDGES_PER_THREAD;
    if (base + EDGES_PER_THREAD <= N_EDGES) {
        int4 r = *reinterpret_cast<const int4*>(rows + base);
        atomicAdd(&cnt[r.x], 1);
        atomicAdd(&cnt[r.y], 1);
        atomicAdd(&cnt[r.z], 1);
        atomicAdd(&cnt[r.w], 1);
    } else {
        for (int e = base; e < N_EDGES; e++) atomicAdd(&cnt[rows[e]], 1);
    }
}

// ---------------------------------------------------------------- scan
__global__ __launch_bounds__(256) void scan_blocks(const int* __restrict__ in,
                                                   int* __restrict__ out,
                                                   int* __restrict__ blk, int n) {
    __shared__ int sdata[256];
    int t = threadIdx.x;
    int base = blockIdx.x * 1024 + t * 4;
    int v[4];
#pragma unroll
    for (int i = 0; i < 4; i++) {
        int idx = base + i;
        v[i] = (idx < n) ? in[idx] : 0;
    }
    int s = v[0] + v[1] + v[2] + v[3];
    sdata[t] = s;
    __syncthreads();
    for (int off = 1; off < 256; off <<= 1) {
        int x = (t >= off) ? sdata[t - off] : 0;
        __syncthreads();
        sdata[t] += x;
        __syncthreads();
    }
    int excl = sdata[t] - s;
#pragma unroll
    for (int i = 0; i < 4; i++) {
        int idx = base + i;
        if (idx < n) { out[idx] = excl; excl += v[i]; }
    }
    if (t == 255) blk[blockIdx.x] = sdata[255];
}

// add block offsets; also duplicate result into the atomic cursor array and
// cap row_ptr[N_NODES].
__global__ __launch_bounds__(256) void scan_add2(int* __restrict__ row_ptr,
                                                 const int* __restrict__ blk,
                                                 int* __restrict__ cur, int n) {
    int i = blockIdx.x * 256 + threadIdx.x;
    if (i < n) {
        int v = row_ptr[i] + blk[i >> 10];
        row_ptr[i] = v;
        cur[i] = v;
    }
    if (i == 0) row_ptr[n] = N_EDGES;
}

// ---------------------------------------------------------------- scatter
// Direct CSR scatter: pos = atomicAdd(cursor[row]); edges[pos] = val<<32|col.
// Within-row order is nondeterministic (same as the old LDS-atomic sort).
__global__ __launch_bounds__(256) void scatter_direct(const int* __restrict__ rows,
                                                      const int* __restrict__ cols,
                                                      const float* __restrict__ vals,
                                                      int* __restrict__ cur,
                                                      ull* __restrict__ edges) {
    int base = (blockIdx.x * 256 + threadIdx.x) * EDGES_PER_THREAD;
    if (base + EDGES_PER_THREAD <= N_EDGES) {
        int4   r4 = *reinterpret_cast<const int4*>(rows + base);
        int4   c4 = *reinterpret_cast<const int4*>(cols + base);
        float4 v4 = *reinterpret_cast<const float4*>(vals + base);
        int p0 = atomicAdd(&cur[r4.x], 1);
        int p1 = atomicAdd(&cur[r4.y], 1);
        int p2 = atomicAdd(&cur[r4.z], 1);
        int p3 = atomicAdd(&cur[r4.w], 1);
        edges[p0] = ((ull)__float_as_uint(v4.x) << 32) | (unsigned)c4.x;
        edges[p1] = ((ull)__float_as_uint(v4.y) << 32) | (unsigned)c4.y;
        edges[p2] = ((ull)__float_as_uint(v4.z) << 32) | (unsigned)c4.z;
        edges[p3] = ((ull)__float_as_uint(v4.w) << 32) | (unsigned)c4.w;
    } else {
        for (int e = base; e < N_EDGES; e++) {
            int pos = atomicAdd(&cur[rows[e]], 1);
            edges[pos] = ((ull)__float_as_uint(vals[e]) << 32) | (unsigned)cols[e];
        }
    }
}

// ------------------------------------------------------------------- GEMM
// MFMA bf16: H[M,64] = X[M,K] @ W[64,K]^T + b, output bf16. X read once.
template <int K, typename XT>
__global__ __launch_bounds__(256) void gemm_mfma(const XT* __restrict__ X,
                                                 const float* __restrict__ W,
                                                 const float* __restrict__ B,
                                                 ushort* __restrict__ H) {
    constexpr int KS = K / 32;
    int wave = threadIdx.x >> 6;
    int lane = threadIdx.x & 63;
    int quad = lane >> 4;
    int l16  = lane & 15;
    int rowBase = blockIdx.x * 64 + wave * 16;
    int arow = rowBase + l16;
    if (arow > N_NODES - 1) arow = N_NODES - 1;   // clamp OOB loads (stores guarded)

    short8 a[KS];
#pragma unroll
    for (int ks = 0; ks < KS; ks++) {
        int k = ks * 32 + quad * 8;
        if constexpr (sizeof(XT) == 2) {
            a[ks] = *reinterpret_cast<const short8*>(X + (size_t)arow * K + k);
        } else {
            const float4* src = reinterpret_cast<const float4*>(X + (size_t)arow * K + k);
            float4 t0 = src[0], t1 = src[1];
            union { short8 v; ushort u[8]; } cv;
            cv.u[0] = rne_bf16(t0.x); cv.u[1] = rne_bf16(t0.y);
            cv.u[2] = rne_bf16(t0.z); cv.u[3] = rne_bf16(t0.w);
            cv.u[4] = rne_bf16(t1.x); cv.u[5] = rne_bf16(t1.y);
            cv.u[6] = rne_bf16(t1.z); cv.u[7] = rne_bf16(t1.w);
            a[ks] = cv.v;
        }
    }

    f32x4 acc[4];
#pragma unroll
    for (int nt = 0; nt < 4; nt++) acc[nt] = 0.f;

#pragma unroll
    for (int nt = 0; nt < 4; nt++) {
        int brow = nt * 16 + l16;                 // W row = output channel n
#pragma unroll
        for (int ks = 0; ks < KS; ks++) {
            int k = ks * 32 + quad * 8;
            const float4* src = reinterpret_cast<const float4*>(W + brow * K + k);
            float4 t0 = src[0], t1 = src[1];
            union { short8 v; ushort u[8]; } cv;
            cv.u[0] = rne_bf16(t0.x); cv.u[1] = rne_bf16(t0.y);
            cv.u[2] = rne_bf16(t0.z); cv.u[3] = rne_bf16(t0.w);
            cv.u[4] = rne_bf16(t1.x); cv.u[5] = rne_bf16(t1.y);
            cv.u[6] = rne_bf16(t1.z); cv.u[7] = rne_bf16(t1.w);
            acc[nt] = __builtin_amdgcn_mfma_f32_16x16x32_bf16(a[ks], cv.v, acc[nt], 0, 0, 0);
        }
    }

#pragma unroll
    for (int nt = 0; nt < 4; nt++) {
        int n = nt * 16 + l16;
        float bv = B[n];
#pragma unroll
        for (int reg = 0; reg < 4; reg++) {
            int m = rowBase + quad * 4 + reg;
            if (m < N_NODES) H[(size_t)m * HID + n] = rne_bf16(acc[nt][reg] + bv);
        }
    }
}

// ------------------------------------------------------------------- SpMM
// Row-per-wave, lane = feature, bf16 gathers (128B/edge), 16-deep unroll.
__global__ __launch_bounds__(256) void spmm_relu(const int* __restrict__ row_ptr,
                                                 const ull* __restrict__ edges,
                                                 const ushort* __restrict__ Hin,
                                                 ushort* __restrict__ Xout) {
    int wid  = (blockIdx.x * 256 + threadIdx.x) >> 6;
    int lane = threadIdx.x & 63;
    if (wid >= N_NODES) return;
    int r = __builtin_amdgcn_readfirstlane(wid);  // wave-uniform -> s_loads
    int start = row_ptr[r];
    int end   = row_ptr[r + 1];
    float acc = 0.f;
    int e = start;
    for (; e + 16 <= end; e += 16) {
        ull p[16];
#pragma unroll
        for (int i = 0; i < 16; i++) p[i] = edges[e + i];
        float h[16];
#pragma unroll
        for (int i = 0; i < 16; i++) {
            int c = (int)(unsigned)(p[i] & 0xFFFFFFFFull);
            h[i] = bf2f(Hin[c * HID + lane]);
        }
#pragma unroll
        for (int i = 0; i < 16; i++) {
            float v = __uint_as_float((unsigned)(p[i] >> 32));
            acc += v * h[i];
        }
    }
    for (; e + 4 <= end; e += 4) {
        ull p[4];
#pragma unroll
        for (int i = 0; i < 4; i++) p[i] = edges[e + i];
#pragma unroll
        for (int i = 0; i < 4; i++) {
            int c = (int)(unsigned)(p[i] & 0xFFFFFFFFull);
            float v = __uint_as_float((unsigned)(p[i] >> 32));
            acc += v * bf2f(Hin[c * HID + lane]);
        }
    }
    for (; e < end; e++) {
        ull p = edges[e];
        int c = (int)(unsigned)(p & 0xFFFFFFFFull);
        float v = __uint_as_float((unsigned)(p >> 32));
        acc += v * bf2f(Hin[c * HID + lane]);
    }
    Xout[r * HID + lane] = rne_bf16(fmaxf(acc, 0.f));
}

// ------------------------------------------------------------------- Pool
// Segmented pool over X1+X2+X3 (bf16): lane = feature; batch sorted ->
// one atomicAdd per segment per wave.
__global__ __launch_bounds__(256) void pool_fused(const ushort* __restrict__ X1,
                                                  const ushort* __restrict__ X2,
                                                  const ushort* __restrict__ X3,
                                                  const int* __restrict__ batch,
                                                  float* __restrict__ sums) {
    int lane = threadIdx.x & 63;
    int w = threadIdx.x >> 6;
    int n0 = blockIdx.x * 128 + w * 32;
    if (n0 >= N_NODES) return;
    int n1 = n0 + 32;
    if (n1 > N_NODES) n1 = N_NODES;
    int g_cur = __builtin_amdgcn_readfirstlane(batch[n0]);
    float acc = 0.f;
    for (int n = n0; n < n1; n++) {
        int g = __builtin_amdgcn_readfirstlane(batch[n]);
        if (g != g_cur) {
            atomicAdd(&sums[g_cur * HID + lane], acc);
            acc = 0.f; g_cur = g;
        }
        size_t base = (size_t)n * HID + lane;
        acc += bf2f(X1[base]) + bf2f(X2[base]) + bf2f(X3[base]);
    }
    atomicAdd(&sums[g_cur * HID + lane], acc);
}

// ------------------------------------------------------------------- Head
// Inline binary search for graph boundaries (find_starts folded in).
__global__ __launch_bounds__(64) void head_kernel(const float* __restrict__ sums,
                                                  const int* __restrict__ batch,
                                                  const float* __restrict__ Wout,
                                                  const float* __restrict__ bout,
                                                  float* __restrict__ out) {
    int g = blockIdx.x;
    int t = threadIdx.x;
    __shared__ float pr[HID];
    __shared__ float lg[OUT_DIM];
    __shared__ float mx, sm;
    auto lb = [&](int key) {
        int lo = 0, hi = N_NODES;
        while (lo < hi) {
            int mid = (lo + hi) >> 1;
            if (batch[mid] < key) lo = mid + 1; else hi = mid;
        }
        return lo;
    };
    int cnt = lb(g + 1) - lb(g);
    float denom = 3.0f * (float)(cnt > 1 ? cnt : 1);
    pr[t] = sums[g * HID + t] / denom;
    __syncthreads();
    if (t < OUT_DIM) {
        float a = bout[t];
        for (int k = 0; k < HID; k++) a += pr[k] * Wout[t * HID + k];
        lg[t] = a;
    }
    __syncthreads();
    if (t == 0) {
        float m = lg[0];
        for (int j = 1; j < OUT_DIM; j++) m = fmaxf(m, lg[j]);
        float s = 0.f;
        for (int j = 0; j < OUT_DIM; j++) s += expf(lg[j] - m);
        mx = m; sm = s;
    }
    __syncthreads();
    if (t < OUT_DIM) out[g * OUT_DIM + t] = expf(lg[t] - mx) / sm;
}

// ---------------------------------------------------------------- launcher
extern "C" void kernel_launch(void* const* d_in, const int* in_sizes, int n_in,
                              void* d_out, int out_size, void* d_ws, size_t ws_size,
                              hipStream_t stream) {
    const float* X    = (const float*)d_in[0];
    const float* vals = (const float*)d_in[1];
    const float* W1   = (const float*)d_in[2];
    const float* b1   = (const float*)d_in[3];
    const float* W2   = (const float*)d_in[4];
    const float* b2   = (const float*)d_in[5];
    const float* W3   = (const float*)d_in[6];
    const float* b3   = (const float*)d_in[7];
    const float* Wout = (const float*)d_in[8];
    const float* bout = (const float*)d_in[9];
    const int*   rows = (const int*)d_in[10];
    const int*   cols = (const int*)d_in[11];
    const int*   batch= (const int*)d_in[12];
    float* out = (float*)d_out;

    char* p = (char*)d_ws;
    auto carve = [&](size_t bytes) {
        void* q = (void*)p;
        p += (bytes + 255) & ~(size_t)255;
        return q;
    };
    ushort* h     = (ushort*)carve((size_t)N_NODES * HID * 2);
    ushort* X1    = (ushort*)carve((size_t)N_NODES * HID * 2);
    ushort* X2    = (ushort*)carve((size_t)N_NODES * HID * 2);
    ushort* X3    = (ushort*)carve((size_t)N_NODES * HID * 2);
    int*   cnt    = (int*)  carve((size_t)N_NODES * 4);
    int*   cur    = (int*)  carve((size_t)N_NODES * 4);
    int*   row_ptr= (int*)  carve((size_t)(N_NODES + 1) * 4);
    int*   blkA   = (int*)  carve(1024 * 4);
    int*   blkB   = (int*)  carve(1024 * 4);
    float* sums   = (float*)carve(N_GRAPHS * HID * 4);
    ull*   edges  = (ull*)  carve((size_t)N_EDGES * 8);
    (void)ws_size; (void)in_sizes; (void)n_in; (void)out_size;

    // ---- build CSR: hist (global atomics) -> scan -> direct scatter
    hipMemsetAsync(cnt, 0, (size_t)N_NODES * 4, stream);
    hist_direct<<<HIST_GRID, 256, 0, stream>>>(rows, cnt);
    scan_blocks<<<NSCAN_NODES, 256, 0, stream>>>(cnt, row_ptr, blkA, N_NODES);
    scan_blocks<<<1, 256, 0, stream>>>(blkA, blkA, blkB, NSCAN_NODES);
    scan_add2<<<(N_NODES + 255) / 256, 256, 0, stream>>>(row_ptr, blkA, cur, N_NODES);
    scatter_direct<<<HIST_GRID, 256, 0, stream>>>(rows, cols, vals, cur, edges);

    const int gemm_grid = (N_NODES + 63) / 64;   // 64 rows/block
    const int spmm_grid = (N_NODES + 3) / 4;

    // ---- layers (X_l kept separately; pooling sums them later)
    gemm_mfma<IN_DIM, float><<<gemm_grid, 256, 0, stream>>>(X, W1, b1, h);
    spmm_relu<<<spmm_grid, 256, 0, stream>>>(row_ptr, edges, h, X1);
    gemm_mfma<HID, ushort><<<gemm_grid, 256, 0, stream>>>(X1, W2, b2, h);
    spmm_relu<<<spmm_grid, 256, 0, stream>>>(row_ptr, edges, h, X2);
    gemm_mfma<HID, ushort><<<gemm_grid, 256, 0, stream>>>(X2, W3, b3, h);
    spmm_relu<<<spmm_grid, 256, 0, stream>>>(row_ptr, edges, h, X3);

    // ---- pool + head
    hipMemsetAsync(sums, 0, N_GRAPHS * HID * 4, stream);
    pool_fused<<<(N_NODES + 127) / 128, 256, 0, stream>>>(X1, X2, X3, batch, sums);
    head_kernel<<<N_GRAPHS, 64, 0, stream>>>(sums, batch, Wout, bout, out);
}

// Round 2
// 442.732 us; speedup vs baseline: 1.7768x; 1.7768x over previous
//
#include <hip/hip_runtime.h>
#include <hip/hip_bf16.h>
#include <math.h>

#define N_NODES   100000
#define N_EDGES   3200000
#define IN_DIM    128
#define HID       64
#define OUT_DIM   10
#define N_GRAPHS  64

// Radix geometry: bucket = row >> 8 (256 rows/bucket), NBUCKET=391.
// Tile = 6250 edges so NTILES=512 = exactly 2 blocks/CU (balanced, resident).
// Both scatter passes permute through LDS so all global stores are coalesced
// (round-1 lesson: random 8B global stores cost a full 64B line each -> 8x
// write amplification and 286us; LDS-staged runs avoid it).
#define BUCKET_SHIFT 8
#define BUCKET_ROWS  256
#define NBUCKET ((N_NODES + BUCKET_ROWS - 1) >> BUCKET_SHIFT)     // 391
#define TILE_EDGES 6250                                           // 512*6250 = 3.2M exact
#define NTILES (N_EDGES / TILE_EDGES)                             // 512
#define NH (NBUCKET * NTILES)                                     // 200,192
#define NSCAN1 ((NH + 1023) / 1024)                               // 196
#define CAP  9216     // bucket mean 8192, sigma ~90 -> 11-sigma margin
#define KMAX 18       // CAP / 512

typedef unsigned long long ull;
typedef unsigned short ushort;
typedef __attribute__((ext_vector_type(8))) short short8;   // 8 bf16 (4 VGPRs)
typedef __attribute__((ext_vector_type(4))) float f32x4;    // MFMA C/D

__device__ __forceinline__ ushort rne_bf16(float x) {
    unsigned u = __float_as_uint(x);
    return (ushort)((u + 0x7fffu + ((u >> 16) & 1u)) >> 16);
}
__device__ __forceinline__ float bf2f(ushort u) {
    return __uint_as_float((unsigned)u << 16);
}

// ---------------------------------------------------------------- pass A
// Per-tile LDS histogram; write histT[tile][bucket] (coalesced).
__global__ __launch_bounds__(1024) void hist_pass(const int* __restrict__ rows,
                                                  int* __restrict__ histT) {
    __shared__ int h[NBUCKET];
    int tid = threadIdx.x, tile = blockIdx.x;
    for (int i = tid; i < NBUCKET; i += 1024) h[i] = 0;
    __syncthreads();
    int base = tile * TILE_EDGES;
#pragma unroll
    for (int k = 0; k < 7; k++) {
        int idx = k * 1024 + tid;
        if (idx < TILE_EDGES) atomicAdd(&h[rows[base + idx] >> BUCKET_SHIFT], 1);
    }
    __syncthreads();
    for (int i = tid; i < NBUCKET; i += 1024) histT[tile * NBUCKET + i] = h[i];
}

// ---------------------------------------------------------------- transpose
__global__ __launch_bounds__(1024) void transpose_int(const int* __restrict__ in,
                                                      int* __restrict__ out,
                                                      int R, int C) {
    __shared__ int tile[32][33];
    int tx = threadIdx.x, ty = threadIdx.y;
    int r = blockIdx.y * 32 + ty, c = blockIdx.x * 32 + tx;
    if (r < R && c < C) tile[ty][tx] = in[r * C + c];
    __syncthreads();
    int rr = blockIdx.y * 32 + tx, cc = blockIdx.x * 32 + ty;
    if (cc < C && rr < R) out[cc * R + rr] = tile[tx][ty];
}

// ---------------------------------------------------------------- scan
__global__ __launch_bounds__(256) void scan_blocks(const int* __restrict__ in,
                                                   int* __restrict__ out,
                                                   int* __restrict__ blk, int n) {
    __shared__ int sdata[256];
    int t = threadIdx.x;
    int base = blockIdx.x * 1024 + t * 4;
    int v[4];
#pragma unroll
    for (int i = 0; i < 4; i++) {
        int idx = base + i;
        v[i] = (idx < n) ? in[idx] : 0;
    }
    int s = v[0] + v[1] + v[2] + v[3];
    sdata[t] = s;
    __syncthreads();
    for (int off = 1; off < 256; off <<= 1) {
        int x = (t >= off) ? sdata[t - off] : 0;
        __syncthreads();
        sdata[t] += x;
        __syncthreads();
    }
    int excl = sdata[t] - s;
#pragma unroll
    for (int i = 0; i < 4; i++) {
        int idx = base + i;
        if (idx < n) { out[idx] = excl; excl += v[i]; }
    }
    if (t == 255) blk[blockIdx.x] = sdata[255];
}

__global__ __launch_bounds__(256) void scan_add(int* __restrict__ data,
                                                const int* __restrict__ blk, int n) {
    int i = blockIdx.x * 256 + threadIdx.x;
    if (i < n) data[i] += blk[i >> 10];
}

// ---------------------------------------------------------------- pass B
// Block-local counting sort by bucket into LDS, then coalesced write-out.
// gdst[pos] = pos + (globalBase[b] - localOff[b]) precomputed per bucket.
__global__ __launch_bounds__(1024) void scatter_pass(const int* __restrict__ rows,
                                                     const int* __restrict__ cols,
                                                     const float* __restrict__ vals,
                                                     const int* __restrict__ histT,
                                                     const int* __restrict__ cursorT,
                                                     ull* __restrict__ etmp) {
    __shared__ ull ebuf[TILE_EDGES];       // 50,000 B
    __shared__ int gdst[TILE_EDGES];       // 25,000 B
    __shared__ int sc[512];                //  2,048 B
    __shared__ int gdelta[NBUCKET];        //  1,564 B
    __shared__ int lcur[NBUCKET];          //  1,564 B  (total ~80.2 KB -> 2 blk/CU)
    int t = threadIdx.x, tile = blockIdx.x;

    int cntv = 0;
    if (t < 512) {
        cntv = (t < NBUCKET) ? histT[tile * NBUCKET + t] : 0;
        sc[t] = cntv;
    }
    __syncthreads();
    for (int off = 1; off < 512; off <<= 1) {
        int x = 0;
        if (t < 512 && t >= off) x = sc[t - off];
        __syncthreads();
        if (t < 512) sc[t] += x;
        __syncthreads();
    }
    if (t < NBUCKET) {
        int excl = sc[t] - cntv;           // local exclusive offset of bucket t
        lcur[t] = excl;
        gdelta[t] = cursorT[tile * NBUCKET + t] - excl;
    }
    __syncthreads();

    int base = tile * TILE_EDGES;
#pragma unroll
    for (int k = 0; k < 7; k++) {
        int idx = k * 1024 + t;
        if (idx < TILE_EDGES) {
            int e = base + idx;
            int r = rows[e];
            int b = r >> BUCKET_SHIFT;
            int pos = atomicAdd(&lcur[b], 1);     // LDS atomic, block-local
            unsigned hi = ((unsigned)(r & (BUCKET_ROWS - 1)) << 24) | (unsigned)cols[e];
            ebuf[pos] = ((ull)hi << 32) | (ull)__float_as_uint(vals[e]);
            gdst[pos] = pos + gdelta[b];
        }
    }
    __syncthreads();
    for (int j = t; j < TILE_EDGES; j += 1024)
        etmp[gdst[j]] = ebuf[j];           // consecutive j -> consecutive dst in runs
}

// ---------------------------------------------------------------- pass C
// One 512-thr block per 256-row bucket: read ~8.2k edges once into registers,
// counting-sort into LDS by local row, write out perfectly coalesced.
__global__ __launch_bounds__(512) void bucket_sort(const int* __restrict__ histL,
                                                   const ull* __restrict__ etmp,
                                                   ull* __restrict__ edges,
                                                   int* __restrict__ row_ptr) {
    __shared__ int rcnt[BUCKET_ROWS];
    __shared__ int roff[BUCKET_ROWS];
    __shared__ int rcur[BUCKET_ROWS];
    __shared__ ull ebuf[CAP];              // 73,728 B -> 2 blk/CU
    int b = blockIdx.x, t = threadIdx.x;
    int s = histL[b * NTILES];
    int e = (b + 1 < NBUCKET) ? histL[(b + 1) * NTILES] : N_EDGES;
    int len = e - s;
    bool staged = (len <= CAP);

    ull rp[KMAX];
    if (t < BUCKET_ROWS) rcnt[t] = 0;
    __syncthreads();
    if (staged) {
#pragma unroll
        for (int k = 0; k < KMAX; k++) {
            int j = s + t + k * 512;
            if (j < e) { rp[k] = etmp[j]; atomicAdd(&rcnt[(int)(rp[k] >> 56)], 1); }
        }
    } else {
        for (int j = s + t; j < e; j += 512)
            atomicAdd(&rcnt[(int)(etmp[j] >> 56)], 1);
    }
    __syncthreads();
    if (t < BUCKET_ROWS) roff[t] = rcnt[t];
    __syncthreads();
    for (int off = 1; off < BUCKET_ROWS; off <<= 1) {
        int x = (t >= off && t < BUCKET_ROWS) ? roff[t - off] : 0;
        __syncthreads();
        if (t < BUCKET_ROWS) roff[t] += x;
        __syncthreads();
    }
    if (t < BUCKET_ROWS) {
        int excl = roff[t] - rcnt[t];
        rcur[t] = staged ? excl : s + excl;
        int grow = b * BUCKET_ROWS + t;
        if (grow < N_NODES) row_ptr[grow] = s + excl;
    }
    if (b == NBUCKET - 1 && t == 0) row_ptr[N_NODES] = N_EDGES;
    __syncthreads();

    if (staged) {
#pragma unroll
        for (int k = 0; k < KMAX; k++) {
            int j = s + t + k * 512;
            if (j < e) {
                ull p = rp[k];
                int rl = (int)(p >> 56);
                unsigned col = (unsigned)(p >> 32) & 0xFFFFFFu;
                int pos = atomicAdd(&rcur[rl], 1);    // LDS atomic, local pos
                ebuf[pos] = ((p & 0xFFFFFFFFull) << 32) | (ull)col;
            }
        }
        __syncthreads();
        for (int j = t; j < len; j += 512)
            edges[s + j] = ebuf[j];                   // coalesced
    } else {
        // statistically unreachable fallback (len > CAP): direct scatter
        for (int j = s + t; j < e; j += 512) {
            ull p = etmp[j];
            int rl = (int)(p >> 56);
            unsigned col = (unsigned)(p >> 32) & 0xFFFFFFu;
            int pos = atomicAdd(&rcur[rl], 1);
            edges[pos] = ((p & 0xFFFFFFFFull) << 32) | (ull)col;
        }
    }
}

// ------------------------------------------------------------------- GEMM
// MFMA bf16: H[M,64] = X[M,K] @ W[64,K]^T + b, output bf16. X read once.
template <int K, typename XT>
__global__ __launch_bounds__(256) void gemm_mfma(const XT* __restrict__ X,
                                                 const float* __restrict__ W,
                                                 const float* __restrict__ B,
                                                 ushort* __restrict__ H) {
    constexpr int KS = K / 32;
    int wave = threadIdx.x >> 6;
    int lane = threadIdx.x & 63;
    int quad = lane >> 4;
    int l16  = lane & 15;
    int rowBase = blockIdx.x * 64 + wave * 16;
    int arow = rowBase + l16;
    if (arow > N_NODES - 1) arow = N_NODES - 1;   // clamp OOB loads (stores guarded)

    short8 a[KS];
#pragma unroll
    for (int ks = 0; ks < KS; ks++) {
        int k = ks * 32 + quad * 8;
        if constexpr (sizeof(XT) == 2) {
            a[ks] = *reinterpret_cast<const short8*>(X + (size_t)arow * K + k);
        } else {
            const float4* src = reinterpret_cast<const float4*>(X + (size_t)arow * K + k);
            float4 t0 = src[0], t1 = src[1];
            union { short8 v; ushort u[8]; } cv;
            cv.u[0] = rne_bf16(t0.x); cv.u[1] = rne_bf16(t0.y);
            cv.u[2] = rne_bf16(t0.z); cv.u[3] = rne_bf16(t0.w);
            cv.u[4] = rne_bf16(t1.x); cv.u[5] = rne_bf16(t1.y);
            cv.u[6] = rne_bf16(t1.z); cv.u[7] = rne_bf16(t1.w);
            a[ks] = cv.v;
        }
    }

    f32x4 acc[4];
#pragma unroll
    for (int nt = 0; nt < 4; nt++) acc[nt] = 0.f;

#pragma unroll
    for (int nt = 0; nt < 4; nt++) {
        int brow = nt * 16 + l16;                 // W row = output channel n
#pragma unroll
        for (int ks = 0; ks < KS; ks++) {
            int k = ks * 32 + quad * 8;
            const float4* src = reinterpret_cast<const float4*>(W + brow * K + k);
            float4 t0 = src[0], t1 = src[1];
            union { short8 v; ushort u[8]; } cv;
            cv.u[0] = rne_bf16(t0.x); cv.u[1] = rne_bf16(t0.y);
            cv.u[2] = rne_bf16(t0.z); cv.u[3] = rne_bf16(t0.w);
            cv.u[4] = rne_bf16(t1.x); cv.u[5] = rne_bf16(t1.y);
            cv.u[6] = rne_bf16(t1.z); cv.u[7] = rne_bf16(t1.w);
            acc[nt] = __builtin_amdgcn_mfma_f32_16x16x32_bf16(a[ks], cv.v, acc[nt], 0, 0, 0);
        }
    }

#pragma unroll
    for (int nt = 0; nt < 4; nt++) {
        int n = nt * 16 + l16;
        float bv = B[n];
#pragma unroll
        for (int reg = 0; reg < 4; reg++) {
            int m = rowBase + quad * 4 + reg;
            if (m < N_NODES) H[(size_t)m * HID + n] = rne_bf16(acc[nt][reg] + bv);
        }
    }
}

// ------------------------------------------------------------------- SpMM
// Row-per-wave, lane = feature, bf16 gathers (128B/edge), 16-deep unroll.
__global__ __launch_bounds__(256) void spmm_relu(const int* __restrict__ row_ptr,
                                                 const ull* __restrict__ edges,
                                                 const ushort* __restrict__ Hin,
                                                 ushort* __restrict__ Xout) {
    int wid  = (blockIdx.x * 256 + threadIdx.x) >> 6;
    int lane = threadIdx.x & 63;
    if (wid >= N_NODES) return;
    int r = __builtin_amdgcn_readfirstlane(wid);  // wave-uniform -> s_loads
    int start = row_ptr[r];
    int end   = row_ptr[r + 1];
    float acc = 0.f;
    int e = start;
    for (; e + 16 <= end; e += 16) {
        ull p[16];
#pragma unroll
        for (int i = 0; i < 16; i++) p[i] = edges[e + i];
        float h[16];
#pragma unroll
        for (int i = 0; i < 16; i++) {
            int c = (int)(unsigned)(p[i] & 0xFFFFFFFFull);
            h[i] = bf2f(Hin[c * HID + lane]);
        }
#pragma unroll
        for (int i = 0; i < 16; i++) {
            float v = __uint_as_float((unsigned)(p[i] >> 32));
            acc += v * h[i];
        }
    }
    for (; e + 4 <= end; e += 4) {
        ull p[4];
#pragma unroll
        for (int i = 0; i < 4; i++) p[i] = edges[e + i];
#pragma unroll
        for (int i = 0; i < 4; i++) {
            int c = (int)(unsigned)(p[i] & 0xFFFFFFFFull);
            float v = __uint_as_float((unsigned)(p[i] >> 32));
            acc += v * bf2f(Hin[c * HID + lane]);
        }
    }
    for (; e < end; e++) {
        ull p = edges[e];
        int c = (int)(unsigned)(p & 0xFFFFFFFFull);
        float v = __uint_as_float((unsigned)(p >> 32));
        acc += v * bf2f(Hin[c * HID + lane]);
    }
    Xout[r * HID + lane] = rne_bf16(fmaxf(acc, 0.f));
}

// ------------------------------------------------------------------- Pool
__global__ __launch_bounds__(256) void pool_fused(const ushort* __restrict__ X1,
                                                  const ushort* __restrict__ X2,
                                                  const ushort* __restrict__ X3,
                                                  const int* __restrict__ batch,
                                                  float* __restrict__ sums) {
    int lane = threadIdx.x & 63;
    int w = threadIdx.x >> 6;
    int n0 = blockIdx.x * 128 + w * 32;
    if (n0 >= N_NODES) return;
    int n1 = n0 + 32;
    if (n1 > N_NODES) n1 = N_NODES;
    int g_cur = __builtin_amdgcn_readfirstlane(batch[n0]);
    float acc = 0.f;
    for (int n = n0; n < n1; n++) {
        int g = __builtin_amdgcn_readfirstlane(batch[n]);
        if (g != g_cur) {
            atomicAdd(&sums[g_cur * HID + lane], acc);
            acc = 0.f; g_cur = g;
        }
        size_t base = (size_t)n * HID + lane;
        acc += bf2f(X1[base]) + bf2f(X2[base]) + bf2f(X3[base]);
    }
    atomicAdd(&sums[g_cur * HID + lane], acc);
}

// ------------------------------------------------------------------- Head
__global__ __launch_bounds__(64) void head_kernel(const float* __restrict__ sums,
                                                  const int* __restrict__ batch,
                                                  const float* __restrict__ Wout,
                                                  const float* __restrict__ bout,
                                                  float* __restrict__ out) {
    int g = blockIdx.x;
    int t = threadIdx.x;
    __shared__ float pr[HID];
    __shared__ float lg[OUT_DIM];
    __shared__ float mx, sm;
    auto lb = [&](int key) {
        int lo = 0, hi = N_NODES;
        while (lo < hi) {
            int mid = (lo + hi) >> 1;
            if (batch[mid] < key) lo = mid + 1; else hi = mid;
        }
        return lo;
    };
    int cnt = lb(g + 1) - lb(g);
    float denom = 3.0f * (float)(cnt > 1 ? cnt : 1);
    pr[t] = sums[g * HID + t] / denom;
    __syncthreads();
    if (t < OUT_DIM) {
        float a = bout[t];
        for (int k = 0; k < HID; k++) a += pr[k] * Wout[t * HID + k];
        lg[t] = a;
    }
    __syncthreads();
    if (t == 0) {
        float m = lg[0];
        for (int j = 1; j < OUT_DIM; j++) m = fmaxf(m, lg[j]);
        float s = 0.f;
        for (int j = 0; j < OUT_DIM; j++) s += expf(lg[j] - m);
        mx = m; sm = s;
    }
    __syncthreads();
    if (t < OUT_DIM) out[g * OUT_DIM + t] = expf(lg[t] - mx) / sm;
}

// ---------------------------------------------------------------- launcher
extern "C" void kernel_launch(void* const* d_in, const int* in_sizes, int n_in,
                              void* d_out, int out_size, void* d_ws, size_t ws_size,
                              hipStream_t stream) {
    const float* X    = (const float*)d_in[0];
    const float* vals = (const float*)d_in[1];
    const float* W1   = (const float*)d_in[2];
    const float* b1   = (const float*)d_in[3];
    const float* W2   = (const float*)d_in[4];
    const float* b2   = (const float*)d_in[5];
    const float* W3   = (const float*)d_in[6];
    const float* b3   = (const float*)d_in[7];
    const float* Wout = (const float*)d_in[8];
    const float* bout = (const float*)d_in[9];
    const int*   rows = (const int*)d_in[10];
    const int*   cols = (const int*)d_in[11];
    const int*   batch= (const int*)d_in[12];
    float* out = (float*)d_out;

    char* p = (char*)d_ws;
    auto carve = [&](size_t bytes) {
        void* q = (void*)p;
        p += (bytes + 255) & ~(size_t)255;
        return q;
    };
    ushort* h     = (ushort*)carve((size_t)N_NODES * HID * 2);
    ushort* X1    = (ushort*)carve((size_t)N_NODES * HID * 4);  // oversized: aliases etmp
    ushort* X2    = (ushort*)carve((size_t)N_NODES * HID * 2);
    ushort* X3    = (ushort*)carve((size_t)N_NODES * HID * 2);
    int*   bufA   = (int*)  carve((size_t)NH * 4);   // histT (tile-major)
    int*   bufB   = (int*)  carve((size_t)NH * 4);   // scanned (bucket-major)
    int*   bufC   = (int*)  carve((size_t)NH * 4);   // cursorT (tile-major)
    int*   row_ptr= (int*)  carve((size_t)(N_NODES + 1) * 4);
    int*   blkA   = (int*)  carve(1024 * 4);
    int*   blkB   = (int*)  carve(1024 * 4);
    float* sums   = (float*)carve(N_GRAPHS * HID * 4);
    ull*   edges  = (ull*)  carve((size_t)N_EDGES * 8);
    // etmp aliases X1: etmp dead (after bucket_sort) before spmm1 writes X1.
    ull*   etmp   = (ull*)X1;
    (void)ws_size; (void)in_sizes; (void)n_in; (void)out_size;

    // ---- build: hist[tile][bucket] -> transpose -> scan -> transpose ->
    //      LDS-sorted scatter (coalesced) -> per-bucket LDS sort (coalesced)
    hist_pass<<<NTILES, 1024, 0, stream>>>(rows, bufA);
    transpose_int<<<dim3((NBUCKET + 31) / 32, (NTILES + 31) / 32), dim3(32, 32), 0, stream>>>(bufA, bufB, NTILES, NBUCKET);
    scan_blocks<<<NSCAN1, 256, 0, stream>>>(bufB, bufB, blkA, NH);
    scan_blocks<<<1, 256, 0, stream>>>(blkA, blkA, blkB, NSCAN1);
    scan_add<<<(NH + 255) / 256, 256, 0, stream>>>(bufB, blkA, NH);
    transpose_int<<<dim3((NTILES + 31) / 32, (NBUCKET + 31) / 32), dim3(32, 32), 0, stream>>>(bufB, bufC, NBUCKET, NTILES);
    scatter_pass<<<NTILES, 1024, 0, stream>>>(rows, cols, vals, bufA, bufC, etmp);
    bucket_sort<<<NBUCKET, 512, 0, stream>>>(bufB, etmp, edges, row_ptr);

    const int gemm_grid = (N_NODES + 63) / 64;   // 64 rows/block
    const int spmm_grid = (N_NODES + 3) / 4;

    // ---- layers (X_l kept separately; pooling sums them later)
    gemm_mfma<IN_DIM, float><<<gemm_grid, 256, 0, stream>>>(X, W1, b1, h);
    spmm_relu<<<spmm_grid, 256, 0, stream>>>(row_ptr, edges, h, X1);
    gemm_mfma<HID, ushort><<<gemm_grid, 256, 0, stream>>>(X1, W2, b2, h);
    spmm_relu<<<spmm_grid, 256, 0, stream>>>(row_ptr, edges, h, X2);
    gemm_mfma<HID, ushort><<<gemm_grid, 256, 0, stream>>>(X2, W3, b3, h);
    spmm_relu<<<spmm_grid, 256, 0, stream>>>(row_ptr, edges, h, X3);

    // ---- pool + head
    hipMemsetAsync(sums, 0, N_GRAPHS * HID * 4, stream);
    pool_fused<<<(N_NODES + 127) / 128, 256, 0, stream>>>(X1, X2, X3, batch, sums);
    head_kernel<<<N_GRAPHS, 64, 0, stream>>>(sums, batch, Wout, bout, out);
}